// Round 14
// baseline (74.039 us; speedup 1.0000x reference)
//
#include <hip/hip_runtime.h>
#include <math.h>

#define GRAVITY_C 9.81007f
#define SIG_G2_C (1.6968e-4f * 1.6968e-4f)
#define SIG_A2_C (2.0e-3f * 2.0e-3f)

// Segment summary (74 floats); phase-2 = suffix-scan + lift + sums (R13),
// split across 2 waves per batch with rotation-free cross-wave merge (R12).
// LDS serialization layout in publish/compose2 -- keep in sync.
struct Seg {
  float q[4];            // 0..3
  float t;               // 4
  float dv[3], dp[3];    // 5..7, 8..10
  float P10[9], P20[9];  // 11..19, 20..28  (after phase2c: half-aggregate N1, N2)
  float c00[6];          // 29..34
  float c01[9];          // 35..43
  float c02[9];          // 44..52
  float c11[6];          // 53..58
  float c12[9];          // 59..67
  float c22[6];          // 68..73
};

static __device__ __forceinline__ void q2m(const float q[4], float R[9]) {
  float x = q[0], y = q[1], z = q[2], w = q[3];
  R[0] = 1.f - 2.f * (y * y + z * z); R[1] = 2.f * (x * y - z * w);       R[2] = 2.f * (x * z + y * w);
  R[3] = 2.f * (x * y + z * w);       R[4] = 1.f - 2.f * (x * x + z * z); R[5] = 2.f * (y * z - x * w);
  R[6] = 2.f * (x * z - y * w);       R[7] = 2.f * (y * z + x * w);       R[8] = 1.f - 2.f * (x * x + y * y);
}

static __device__ __forceinline__ void qmul(const float a[4], const float b[4], float o[4]) {
  float x1 = a[0], y1 = a[1], z1 = a[2], w1 = a[3];
  float x2 = b[0], y2 = b[1], z2 = b[2], w2 = b[3];
  o[0] = w1 * x2 + x1 * w2 + y1 * z2 - z1 * y2;
  o[1] = w1 * y2 - x1 * z2 + y1 * w2 + z1 * x2;
  o[2] = w1 * z2 + x1 * y2 - y1 * x2 + z1 * w2;
  o[3] = w1 * w2 - x1 * x2 - y1 * y2 - z1 * z2;
}

// C = A @ B
static __device__ __forceinline__ void mm(const float A[9], const float B[9], float C[9]) {
#pragma unroll
  for (int i = 0; i < 3; i++)
#pragma unroll
    for (int j = 0; j < 3; j++)
      C[3 * i + j] = A[3 * i + 0] * B[0 + j] + A[3 * i + 1] * B[3 + j] + A[3 * i + 2] * B[6 + j];
}
// C = A @ B^T
static __device__ __forceinline__ void mmT(const float A[9], const float B[9], float C[9]) {
#pragma unroll
  for (int i = 0; i < 3; i++)
#pragma unroll
    for (int j = 0; j < 3; j++)
      C[3 * i + j] = A[3 * i + 0] * B[3 * j + 0] + A[3 * i + 1] * B[3 * j + 1] + A[3 * i + 2] * B[3 * j + 2];
}
// C = A^T @ B
static __device__ __forceinline__ void mTm(const float A[9], const float B[9], float C[9]) {
#pragma unroll
  for (int i = 0; i < 3; i++)
#pragma unroll
    for (int j = 0; j < 3; j++)
      C[3 * i + j] = A[0 + i] * B[0 + j] + A[3 + i] * B[3 + j] + A[6 + i] * B[6 + j];
}

static __device__ __forceinline__ void expand6(const float c[6], float f[9]) {
  f[0] = c[0]; f[1] = c[1]; f[2] = c[2];
  f[3] = c[1]; f[4] = c[3]; f[5] = c[4];
  f[6] = c[2]; f[7] = c[4]; f[8] = c[5];
}

__device__ __constant__ const int SI6[6] = {0, 0, 0, 1, 1, 2};
__device__ __constant__ const int SJ6[6] = {0, 1, 2, 1, 2, 2};

// One IMU step in hat frame (verified R6-R13). Ro recomputed from s.q
// (live-set diet for the 128-reg budget; R12 proof point).
static __device__ __forceinline__ void step(Seg& s, float gb[3], float dtv,
                                            float omx, float omy, float omz,
                                            float acx, float acy, float acz) {
  float px = omx * dtv, py = omy * dtv, pz = omz * dtv;
  float t2 = px * px + py * py + pz * pz;
  float s_ = 0.5f - t2 * (1.0f / 48.0f);
  float qd[4] = {px * s_, py * s_, pz * s_, 1.0f - 0.125f * t2};

  float Ro[9]; q2m(s.q, Ro);
  float Rd[9]; q2m(qd, Rd);
  float qn[4]; qmul(s.q, qd, qn);
  float Rn[9]; q2m(qn, Rn);

  float gbn[3];
#pragma unroll
  for (int i = 0; i < 3; i++)
    gbn[i] = Rd[0 + i] * gb[0] + Rd[3 + i] * gb[1] + Rd[6 + i] * gb[2];
  float bx = acx - gbn[0], by = acy - gbn[1], bz = acz - gbn[2];
  float Ra[3];
#pragma unroll
  for (int i = 0; i < 3; i++)
    Ra[i] = Ro[3 * i + 0] * bx + Ro[3 * i + 1] * by + Ro[3 * i + 2] * bz;

  float hdt = 0.5f * dtv;
  float hdt2 = hdt * dtv;
#pragma unroll
  for (int i = 0; i < 3; i++) s.dp[i] += s.dv[i] * dtv + Ra[i] * hdt2;
#pragma unroll
  for (int i = 0; i < 3; i++) s.dv[i] += Ra[i] * dtv;

  float M[9];
#pragma unroll
  for (int i = 0; i < 3; i++) {
    M[3 * i + 0] = -dtv * (Rn[3 * i + 1] * acz - Rn[3 * i + 2] * acy);
    M[3 * i + 1] = -dtv * (-Rn[3 * i + 0] * acz + Rn[3 * i + 2] * acx);
    M[3 * i + 2] = -dtv * (Rn[3 * i + 0] * acy - Rn[3 * i + 1] * acx);
  }

  float TP[9]; mmT(M, Ro, TP);
#pragma unroll
  for (int k = 0; k < 9; k++) s.P20[k] += hdt * TP[k] + dtv * s.P10[k];
#pragma unroll
  for (int k = 0; k < 9; k++) s.P10[k] += TP[k];

  float C00f[9]; expand6(s.c00, C00f);
  float W01[9]; mmT(C00f, TP, W01);
  float Y1h[9]; mm(TP, s.c01, Y1h);
  float Y2h[9]; mm(TP, s.c02, Y2h);

  float Wm6[6];
#pragma unroll
  for (int s6 = 0; s6 < 6; s6++) {
    const int i = SI6[s6], j = SJ6[s6];
    Wm6[s6] = W01[0 + i] * TP[3 * j + 0] + W01[3 + i] * TP[3 * j + 1] + W01[6 + i] * TP[3 * j + 2];
  }
  float WmF[9]; expand6(Wm6, WmF);

#pragma unroll
  for (int k = 0; k < 9; k++) s.c02[k] += hdt * (W01[k] + 2.0f * s.c01[k]);
#pragma unroll
  for (int k = 0; k < 9; k++) s.c01[k] += W01[k];

  {
    float ph[3];
#pragma unroll
    for (int i = 0; i < 3; i++)
      ph[i] = Rn[3 * i + 0] * px + Rn[3 * i + 1] * py + Rn[3 * i + 2] * pz;
    float sgdt2 = SIG_G2_C * dtv * dtv;
    float a_ = sgdt2 * (1.0f - t2 * (1.0f / 12.0f));
    float b_ = sgdt2 * ((1.0f / 12.0f) - t2 * (1.0f / 36.0f));
#pragma unroll
    for (int s6 = 0; s6 < 6; s6++) {
      const int i = SI6[s6], j = SJ6[s6];
      float v = s.c00[s6] + b_ * ph[i] * ph[j];
      if (i == j) v += a_;
      s.c00[s6] = v;
    }
  }

  float C11f[9]; expand6(s.c11, C11f);
  float c11p[9];
#pragma unroll
  for (int i = 0; i < 3; i++)
#pragma unroll
    for (int j = 0; j < 3; j++)
      c11p[3 * i + j] = WmF[3 * i + j] + Y1h[3 * i + j] + Y1h[3 * j + i] + C11f[3 * i + j];

  float c12p[9];
#pragma unroll
  for (int i = 0; i < 3; i++)
#pragma unroll
    for (int j = 0; j < 3; j++)
      c12p[3 * i + j] = hdt * (c11p[3 * i + j] + Y1h[3 * i + j] + C11f[3 * i + j])
                      + Y2h[3 * i + j] + s.c12[3 * i + j];

  float dt2v = dtv * dtv;
  float nh2 = -hdt * hdt;
#pragma unroll
  for (int s6 = 0; s6 < 6; s6++) {
    const int i = SI6[s6], j = SJ6[s6];
    float v = s.c22[s6]
            + hdt * (c12p[3 * i + j] + c12p[3 * j + i] + s.c12[3 * i + j] + s.c12[3 * j + i])
            + nh2 * (c11p[3 * i + j] - C11f[3 * i + j]);
    if (i == j) v += SIG_A2_C * 0.25f * dt2v * dt2v;
    s.c22[s6] = v;
  }
#pragma unroll
  for (int i = 0; i < 3; i++)
#pragma unroll
    for (int j = 0; j < 3; j++) {
      float v = c12p[3 * i + j];
      if (i == j) v += SIG_A2_C * hdt * dt2v;
      s.c12[3 * i + j] = v;
    }
#pragma unroll
  for (int s6 = 0; s6 < 6; s6++) {
    const int i = SI6[s6], j = SJ6[s6];
    float v = c11p[3 * i + j];
    if (i == j) v += SIG_A2_C * dt2v;
    s.c11[s6] = v;
  }

#pragma unroll
  for (int i = 0; i < 4; i++) s.q[i] = qn[i];
#pragma unroll
  for (int i = 0; i < 3; i++) gb[i] = gbn[i];
  s.t += dtv;
}

// full sandwich A <- R A R^T
static __device__ __forceinline__ void sandw(const float R[9], float A[9]) {
  float T1[9]; mm(R, A, T1);
  mmT(T1, R, A);
}

// masked shfl_down: identity (0) when lane+d out of range
static __device__ __forceinline__ float shdn(float v, int d, bool ok) {
  float o = __shfl_down(v, d, 64);
  return ok ? o : 0.0f;
}

// Cross-wave compose (verified R12): X = s (regs, earlier half),
// Y = y[74] (LDS, later half). Seg.P10/P20 hold half-aggregate N1/N2.
static __device__ __forceinline__ void compose2(Seg& s, const float* y) {
  float tY = y[4];
  {
    float xq[4] = {s.q[0], s.q[1], s.q[2], s.q[3]};
    float yq[4] = {y[0], y[1], y[2], y[3]};
    qmul(xq, yq, s.q);
  }
  s.t += tY;
#pragma unroll
  for (int i = 0; i < 3; i++) s.dp[i] += tY * s.dv[i] + y[8 + i];
#pragma unroll
  for (int i = 0; i < 3; i++) s.dv[i] += y[5 + i];

  float N1[9], N2[9];
#pragma unroll
  for (int k = 0; k < 9; k++) { N1[k] = y[11 + k]; N2[k] = y[20 + k]; }

  float X00f[9]; expand6(s.c00, X00f);
  float K1[9]; mm(N1, X00f, K1);
  float K2[9]; mm(N2, X00f, K2);
#pragma unroll
  for (int s6 = 0; s6 < 6; s6++) s.c00[s6] += y[29 + s6];

  float x01[9], x02[9];
#pragma unroll
  for (int k = 0; k < 9; k++) { x01[k] = s.c01[k]; x02[k] = s.c02[k]; }
  float L1[9]; mm(N1, x01, L1);
  float L2[9]; mm(N2, x01, L2);
  float L3[9]; mm(N1, x02, L3);
  float L4[9]; mm(N2, x02, L4);

#pragma unroll
  for (int i = 0; i < 3; i++)
#pragma unroll
    for (int j = 0; j < 3; j++) {
      s.c01[3 * i + j] = x01[3 * i + j] + K1[3 * j + i] + y[35 + 3 * i + j];
      s.c02[3 * i + j] = x02[3 * i + j] + tY * x01[3 * i + j] + K2[3 * j + i] + y[44 + 3 * i + j];
    }

  float x11[6];
#pragma unroll
  for (int s6 = 0; s6 < 6; s6++) x11[s6] = s.c11[s6];
  float X11f[9]; expand6(x11, X11f);
  float x12[9];
#pragma unroll
  for (int k = 0; k < 9; k++) x12[k] = s.c12[k];

#pragma unroll
  for (int s6 = 0; s6 < 6; s6++) {
    const int i = SI6[s6], j = SJ6[s6];
    float kn = K1[3 * i + 0] * N1[3 * j + 0] + K1[3 * i + 1] * N1[3 * j + 1] + K1[3 * i + 2] * N1[3 * j + 2];
    s.c11[s6] = x11[s6] + L1[3 * i + j] + L1[3 * j + i] + kn + y[53 + s6];
  }
#pragma unroll
  for (int i = 0; i < 3; i++)
#pragma unroll
    for (int j = 0; j < 3; j++) {
      float kn = K1[3 * i + 0] * N2[3 * j + 0] + K1[3 * i + 1] * N2[3 * j + 1] + K1[3 * i + 2] * N2[3 * j + 2];
      s.c12[3 * i + j] = x12[3 * i + j] + L3[3 * i + j] + tY * (L1[3 * i + j] + X11f[3 * i + j])
                       + L2[3 * j + i] + kn + y[59 + 3 * i + j];
    }
  float tY2 = tY * tY;
#pragma unroll
  for (int s6 = 0; s6 < 6; s6++) {
    const int i = SI6[s6], j = SJ6[s6];
    float kn = K2[3 * i + 0] * N2[3 * j + 0] + K2[3 * i + 1] * N2[3 * j + 1] + K2[3 * i + 2] * N2[3 * j + 2];
    s.c22[s6] = s.c22[s6] + kn + L4[3 * i + j] + L4[3 * j + i]
              + tY * (L2[3 * i + j] + L2[3 * j + i] + x12[3 * i + j] + x12[3 * j + i])
              + tY2 * X11f[3 * i + j] + y[68 + s6];
  }
  // P10/P20 aggregates not needed past the final merge.
}

// Publish a wave's Seg to LDS with COMPILE-TIME indices only (rule #20).
static __device__ __forceinline__ void publish(const Seg& s, float* o) {
  o[0] = s.q[0]; o[1] = s.q[1]; o[2] = s.q[2]; o[3] = s.q[3];
  o[4] = s.t;
#pragma unroll
  for (int i = 0; i < 3; i++) { o[5 + i] = s.dv[i]; o[8 + i] = s.dp[i]; }
#pragma unroll
  for (int k = 0; k < 9; k++) {
    o[11 + k] = s.P10[k]; o[20 + k] = s.P20[k];
    o[35 + k] = s.c01[k]; o[44 + k] = s.c02[k]; o[59 + k] = s.c12[k];
  }
#pragma unroll
  for (int k = 0; k < 6; k++) {
    o[29 + k] = s.c00[k]; o[53 + k] = s.c11[k]; o[68 + k] = s.c22[k];
  }
}

// 256 threads = 4 waves = 2 batches x 2 half-waves, (B+1)/2 blocks (4096 waves).
// w=2 -> VGPR cap 128 -> 4 waves/SIMD (R12 proved fit with heavier phase 2).
__global__ __launch_bounds__(256, 2) void imu_kernel(
    const float* __restrict__ dt, const float* __restrict__ ang, const float* __restrict__ acc,
    const float* __restrict__ pos0, const float* __restrict__ vel0, const float* __restrict__ rot0,
    float* __restrict__ out, int B, int N) {
  int lane = threadIdx.x & 63;
  int wv = threadIdx.x >> 6;
  int bl = wv >> 1;   // batch slot within block (0..1)
  int hf = wv & 1;    // half index
  int b = blockIdx.x * 2 + bl;
  int chunk = N >> 7; // 8 steps per lane

  __shared__ float lds_qh[2][4];
  __shared__ float lds_seg[2][74];

  long base = (long)b * N + (long)hf * (N >> 1) + (long)lane * chunk;
  const float* dtp = dt + base;
  const float* angp = ang + base * 3;
  const float* accp = acc + base * 3;

  // ---- pre-pass: chunk rotation product ----
  float qc[4] = {0.f, 0.f, 0.f, 1.f};
#pragma unroll 1
  for (int jb = 0; jb < (chunk >> 2); ++jb) {
    float4 d4 = *reinterpret_cast<const float4*>(dtp + jb * 4);
    float4 g0 = *reinterpret_cast<const float4*>(angp + jb * 12 + 0);
    float4 g1 = *reinterpret_cast<const float4*>(angp + jb * 12 + 4);
    float4 g2 = *reinterpret_cast<const float4*>(angp + jb * 12 + 8);
    float dd[4] = {d4.x, d4.y, d4.z, d4.w};
    float gg[12] = {g0.x, g0.y, g0.z, g0.w, g1.x, g1.y, g1.z, g1.w, g2.x, g2.y, g2.z, g2.w};
#pragma unroll
    for (int u = 0; u < 4; ++u) {
      float dtv = dd[u];
      float px = gg[3 * u + 0] * dtv, py = gg[3 * u + 1] * dtv, pz = gg[3 * u + 2] * dtv;
      float t2 = px * px + py * py + pz * pz;
      float s_ = 0.5f - t2 * (1.0f / 48.0f);
      float qd[4] = {px * s_, py * s_, pz * s_, 1.0f - 0.125f * t2};
      float qn[4]; qmul(qc, qd, qn);
      qc[0] = qn[0]; qc[1] = qn[1]; qc[2] = qn[2]; qc[3] = qn[3];
    }
  }
  // inclusive shuffle-up scan (non-commutative)
#pragma unroll
  for (int d = 1; d < 64; d <<= 1) {
    float o0 = __shfl_up(qc[0], d, 64);
    float o1 = __shfl_up(qc[1], d, 64);
    float o2 = __shfl_up(qc[2], d, 64);
    float o3 = __shfl_up(qc[3], d, 64);
    if (lane >= d) {
      float oq[4] = {o0, o1, o2, o3};
      float nn[4]; qmul(oq, qc, nn);
      qc[0] = nn[0]; qc[1] = nn[1]; qc[2] = nn[2]; qc[3] = nn[3];
    }
  }
  // half-total rotation (lane-63 broadcast of LOCAL scan)
  float qT[4];
  qT[0] = __shfl(qc[0], 63, 64);
  qT[1] = __shfl(qc[1], 63, 64);
  qT[2] = __shfl(qc[2], 63, 64);
  qT[3] = __shfl(qc[3], 63, 64);
  // first half publishes its total rotation for the second half's prefix
  if (hf == 0 && lane == 63) {
    lds_qh[bl][0] = qc[0]; lds_qh[bl][1] = qc[1]; lds_qh[bl][2] = qc[2]; lds_qh[bl][3] = qc[3];
  }
  // exclusive local prefix
  float Q[4];
  Q[0] = __shfl_up(qc[0], 1, 64);
  Q[1] = __shfl_up(qc[1], 1, 64);
  Q[2] = __shfl_up(qc[2], 1, 64);
  Q[3] = __shfl_up(qc[3], 1, 64);
  if (lane == 0) { Q[0] = 0.f; Q[1] = 0.f; Q[2] = 0.f; Q[3] = 1.f; }
  __syncthreads();
  if (hf == 1) {
    float q0[4] = {lds_qh[bl][0], lds_qh[bl][1], lds_qh[bl][2], lds_qh[bl][3]};
    float qq[4]; qmul(q0, Q, qq);
    Q[0] = qq[0]; Q[1] = qq[1]; Q[2] = qq[2]; Q[3] = qq[3];
  }

  // per-lane gravity in chunk-start frame: g_l = rot(Q^-1, R0^T g)
  float g_l[3];
  {
    float r0q[4] = {rot0[b * 4 + 0], rot0[b * 4 + 1], rot0[b * 4 + 2], rot0[b * 4 + 3]};
    float R0[9]; q2m(r0q, R0);
    float gp[3] = {R0[6] * GRAVITY_C, R0[7] * GRAVITY_C, R0[8] * GRAVITY_C};
    float qx = -Q[0], qy = -Q[1], qz = -Q[2], qw = Q[3];
    float tx = 2.0f * (qy * gp[2] - qz * gp[1]);
    float ty = 2.0f * (qz * gp[0] - qx * gp[2]);
    float tz = 2.0f * (qx * gp[1] - qy * gp[0]);
    g_l[0] = gp[0] + qw * tx + (qy * tz - qz * ty);
    g_l[1] = gp[1] + qw * ty + (qz * tx - qx * tz);
    g_l[2] = gp[2] + qw * tz + (qx * ty - qy * tx);
  }

  Seg s = {};
  s.q[3] = 1.0f;
  float gb[3] = {g_l[0], g_l[1], g_l[2]};

  // ---- phase 1: 1 step/iter, plain loads (4-wave TLP hides latency) ----
#pragma unroll 1
  for (int j = 0; j < chunk; ++j) {
    float dtv = dtp[j];
    float gx = angp[3 * j + 0], gy = angp[3 * j + 1], gz = angp[3 * j + 2];
    float ax = accp[3 * j + 0], ay = accp[3 * j + 1], az = accp[3 * j + 2];
    step(s, gb, dtv, gx, gy, gz, ax, ay, az);
  }

  // ---- globalize via full-sequence prefix RQ ----
  {
    float RQ[9]; q2m(Q, RQ);
    float tv[3];
#pragma unroll
    for (int i = 0; i < 3; i++)
      tv[i] = RQ[3 * i + 0] * s.dv[0] + RQ[3 * i + 1] * s.dv[1] + RQ[3 * i + 2] * s.dv[2];
#pragma unroll
    for (int i = 0; i < 3; i++) s.dv[i] = tv[i];
#pragma unroll
    for (int i = 0; i < 3; i++)
      tv[i] = RQ[3 * i + 0] * s.dp[0] + RQ[3 * i + 1] * s.dp[1] + RQ[3 * i + 2] * s.dp[2];
#pragma unroll
    for (int i = 0; i < 3; i++) s.dp[i] = tv[i];
    sandw(RQ, s.P10);
    sandw(RQ, s.P20);
    sandw(RQ, s.c01);
    sandw(RQ, s.c02);
    sandw(RQ, s.c12);
    float F[9];
    expand6(s.c00, F); sandw(RQ, F);
    s.c00[0] = F[0]; s.c00[1] = F[1]; s.c00[2] = F[2]; s.c00[3] = F[4]; s.c00[4] = F[5]; s.c00[5] = F[8];
    expand6(s.c11, F); sandw(RQ, F);
    s.c11[0] = F[0]; s.c11[1] = F[1]; s.c11[2] = F[2]; s.c11[3] = F[4]; s.c11[4] = F[5]; s.c11[5] = F[8];
    expand6(s.c22, F); sandw(RQ, F);
    s.c22[0] = F[0]; s.c22[1] = F[1]; s.c22[2] = F[2]; s.c22[3] = F[4]; s.c22[4] = F[5]; s.c22[5] = F[8];
  }

  // ---- phase 2a: suffix scan of (S1, S2, T) over later chunks in this wave ----
  float S1[9], S2[9], Tt;
  {
    bool ok0 = lane < 63;
#pragma unroll
    for (int k = 0; k < 9; k++) {
      S1[k] = shdn(s.P10[k], 1, ok0);
      S2[k] = shdn(s.P20[k], 1, ok0);
    }
    Tt = shdn(s.t, 1, ok0);
#pragma unroll
    for (int d = 1; d < 64; d <<= 1) {
      bool ok = (lane + d) < 64;
      float fT = shdn(Tt, d, ok);
      float fS1[9], fS2[9];
#pragma unroll
      for (int k = 0; k < 9; k++) { fS1[k] = shdn(S1[k], d, ok); fS2[k] = shdn(S2[k], d, ok); }
#pragma unroll
      for (int k = 0; k < 9; k++) S2[k] = fS2[k] + fT * S1[k] + S2[k];
#pragma unroll
      for (int k = 0; k < 9; k++) S1[k] += fS1[k];
      Tt += fT;
    }
  }

  // ---- phase 2b: lift own blocks by P_i = [[I,0,0],[S1,I,0],[S2,Tt*I,I]] ----
  {
    float A9[9]; expand6(s.c00, A9);
    float ASt[9]; mmT(A9, S1, ASt);
    float AZt[9]; mmT(A9, S2, AZt);
    float SB[9];  mm(S1, s.c01, SB);
    float ZB[9];  mm(S2, s.c01, ZB);
    float ZC[9];  mm(S2, s.c02, ZC);
    float D9[9];  expand6(s.c11, D9);

    float r02[9];
#pragma unroll
    for (int k = 0; k < 9; k++) r02[k] = AZt[k] + Tt * s.c01[k] + s.c02[k];
    float Sr02[9]; mm(S1, r02, Sr02);

    float r01[9];
#pragma unroll
    for (int k = 0; k < 9; k++) r01[k] = ASt[k] + s.c01[k];

    float r11[6];
#pragma unroll
    for (int s6 = 0; s6 < 6; s6++) {
      const int i = SI6[s6], j = SJ6[s6];
      float sast = S1[3 * i + 0] * ASt[0 + j] + S1[3 * i + 1] * ASt[3 + j] + S1[3 * i + 2] * ASt[6 + j];
      r11[s6] = sast + SB[3 * i + j] + SB[3 * j + i] + s.c11[s6];
    }
    float r22[6];
#pragma unroll
    for (int s6 = 0; s6 < 6; s6++) {
      const int i = SI6[s6], j = SJ6[s6];
      float zazt = S2[3 * i + 0] * AZt[0 + j] + S2[3 * i + 1] * AZt[3 + j] + S2[3 * i + 2] * AZt[6 + j];
      r22[s6] = zazt + Tt * (ZB[3 * i + j] + ZB[3 * j + i]) + (ZC[3 * i + j] + ZC[3 * j + i])
              + Tt * Tt * D9[3 * i + j] + Tt * (s.c12[3 * i + j] + s.c12[3 * j + i]) + s.c22[s6];
    }
    float r12[9];
#pragma unroll
    for (int i = 0; i < 3; i++)
#pragma unroll
      for (int j = 0; j < 3; j++)
        r12[3 * i + j] = Sr02[3 * i + j] + ZB[3 * j + i] + Tt * D9[3 * i + j] + s.c12[3 * i + j];

#pragma unroll
    for (int k = 0; k < 9; k++) { s.c01[k] = r01[k]; s.c02[k] = r02[k]; s.c12[k] = r12[k]; }
#pragma unroll
    for (int s6 = 0; s6 < 6; s6++) { s.c11[s6] = r11[s6]; s.c22[s6] = r22[s6]; }
#pragma unroll
    for (int i = 0; i < 3; i++) s.dp[i] += Tt * s.dv[i];
    // half-aggregate N2 contribution: z_i = P20_i + Tt_i * P10_i (coupled sum)
#pragma unroll
    for (int k = 0; k < 9; k++) s.P20[k] += Tt * s.P10[k];
  }

  // ---- phase 2c: butterfly sums (cov 45 + dv/dp 6 + t + P10 9 + z 9 = 70) ----
#pragma unroll
  for (int d = 1; d < 64; d <<= 1) {
#pragma unroll
    for (int k = 0; k < 6; k++) s.c00[k] += __shfl_xor(s.c00[k], d, 64);
#pragma unroll
    for (int k = 0; k < 9; k++) s.c01[k] += __shfl_xor(s.c01[k], d, 64);
#pragma unroll
    for (int k = 0; k < 9; k++) s.c02[k] += __shfl_xor(s.c02[k], d, 64);
#pragma unroll
    for (int k = 0; k < 6; k++) s.c11[k] += __shfl_xor(s.c11[k], d, 64);
#pragma unroll
    for (int k = 0; k < 9; k++) s.c12[k] += __shfl_xor(s.c12[k], d, 64);
#pragma unroll
    for (int k = 0; k < 6; k++) s.c22[k] += __shfl_xor(s.c22[k], d, 64);
#pragma unroll
    for (int k = 0; k < 9; k++) { s.P10[k] += __shfl_xor(s.P10[k], d, 64); s.P20[k] += __shfl_xor(s.P20[k], d, 64); }
#pragma unroll
    for (int k = 0; k < 3; k++) { s.dv[k] += __shfl_xor(s.dv[k], d, 64); s.dp[k] += __shfl_xor(s.dp[k], d, 64); }
    s.t += __shfl_xor(s.t, d, 64);
  }
  // set q to the half-total rotation (for publish / final output)
#pragma unroll
  for (int i = 0; i < 4; i++) s.q[i] = qT[i];

  // ---- cross-wave merge: second half publishes (STATIC indices), first composes ----
  if (hf == 1 && lane == 0) publish(s, lds_seg[bl]);
  __syncthreads();

  if (hf == 0 && lane == 0) {
    compose2(s, lds_seg[bl]);

    float r0q[4] = {rot0[b * 4 + 0], rot0[b * 4 + 1], rot0[b * 4 + 2], rot0[b * 4 + 3]};
    float p0[3] = {pos0[b * 3 + 0], pos0[b * 3 + 1], pos0[b * 3 + 2]};
    float v0[3] = {vel0[b * 3 + 0], vel0[b * 3 + 1], vel0[b * 3 + 2]};
    float R0[9]; q2m(r0q, R0);
    float qo[4]; qmul(r0q, s.q, qo);
#pragma unroll
    for (int i = 0; i < 4; i++) out[b * 4 + i] = qo[i];
#pragma unroll
    for (int i = 0; i < 3; i++) {
      float vv = v0[i] + R0[3 * i + 0] * s.dv[0] + R0[3 * i + 1] * s.dv[1] + R0[3 * i + 2] * s.dv[2];
      float pv = p0[i] + v0[i] * s.t + R0[3 * i + 0] * s.dp[0] + R0[3 * i + 1] * s.dp[1] + R0[3 * i + 2] * s.dp[2];
      out[4 * B + b * 3 + i] = vv;
      out[7 * B + b * 3 + i] = pv;
    }
    // convert theta-indexed blocks back to end-body frame convention
    float Rq[9]; q2m(s.q, Rq);
    float C00f[9];
    {
      float G[9]; expand6(s.c00, G);
      float T1[9]; mTm(Rq, G, T1);
      mm(T1, Rq, C00f);
    }
    float C01f[9]; mTm(Rq, s.c01, C01f);
    float C02f[9]; mTm(Rq, s.c02, C02f);
    float C11f[9], C22f[9];
    expand6(s.c11, C11f); expand6(s.c22, C22f);

    long cb = 10L * B + (long)b * 81;
#pragma unroll
    for (int i = 0; i < 3; i++)
#pragma unroll
      for (int j = 0; j < 3; j++) {
        out[cb + i * 9 + j]           = C00f[3 * i + j];
        out[cb + i * 9 + (j + 3)]     = C01f[3 * i + j];
        out[cb + i * 9 + (j + 6)]     = C02f[3 * i + j];
        out[cb + (i + 3) * 9 + j]     = C01f[3 * j + i];
        out[cb + (i + 3) * 9 + j + 3] = C11f[3 * i + j];
        out[cb + (i + 3) * 9 + j + 6] = s.c12[3 * i + j];
        out[cb + (i + 6) * 9 + j]     = C02f[3 * j + i];
        out[cb + (i + 6) * 9 + j + 3] = s.c12[3 * j + i];
        out[cb + (i + 6) * 9 + j + 6] = C22f[3 * i + j];
      }
  }
}

extern "C" void kernel_launch(void* const* d_in, const int* in_sizes, int n_in,
                              void* d_out, int out_size, void* d_ws, size_t ws_size,
                              hipStream_t stream) {
  const float* dt   = (const float*)d_in[0];
  const float* ang  = (const float*)d_in[1];
  const float* acc  = (const float*)d_in[2];
  const float* pos0 = (const float*)d_in[3];
  const float* vel0 = (const float*)d_in[4];
  const float* rot0 = (const float*)d_in[5];
  int B = in_sizes[5] / 4;
  int N = in_sizes[0] / B;
  float* out = (float*)d_out;
  dim3 grid((B + 1) / 2), block(256);
  imu_kernel<<<grid, block, 0, stream>>>(dt, ang, acc, pos0, vel0, rot0, out, B, N);
}

// Round 15
// 72.428 us; speedup vs baseline: 1.0222x; 1.0222x over previous
//
#include <hip/hip_runtime.h>
#include <math.h>

#define GRAVITY_C 9.81007f
#define SIG_G2_C (1.6968e-4f * 1.6968e-4f)
#define SIG_A2_C (2.0e-3f * 2.0e-3f)

// Segment summary (74 floats); phase-2 = suffix-scan + lift + sums (R13),
// split across 2 waves per batch with rotation-free cross-wave merge (R12/R14).
// LDS serialization layout in publish/compose2 -- keep in sync.
struct Seg {
  float q[4];            // 0..3
  float t;               // 4
  float dv[3], dp[3];    // 5..7, 8..10
  float P10[9], P20[9];  // 11..19, 20..28  (after phase2c: half-aggregate N1, N2)
  float c00[6];          // 29..34
  float c01[9];          // 35..43
  float c02[9];          // 44..52
  float c11[6];          // 53..58
  float c12[9];          // 59..67
  float c22[6];          // 68..73
};

static __device__ __forceinline__ void q2m(const float q[4], float R[9]) {
  float x = q[0], y = q[1], z = q[2], w = q[3];
  R[0] = 1.f - 2.f * (y * y + z * z); R[1] = 2.f * (x * y - z * w);       R[2] = 2.f * (x * z + y * w);
  R[3] = 2.f * (x * y + z * w);       R[4] = 1.f - 2.f * (x * x + z * z); R[5] = 2.f * (y * z - x * w);
  R[6] = 2.f * (x * z - y * w);       R[7] = 2.f * (y * z + x * w);       R[8] = 1.f - 2.f * (x * x + y * y);
}

static __device__ __forceinline__ void qmul(const float a[4], const float b[4], float o[4]) {
  float x1 = a[0], y1 = a[1], z1 = a[2], w1 = a[3];
  float x2 = b[0], y2 = b[1], z2 = b[2], w2 = b[3];
  o[0] = w1 * x2 + x1 * w2 + y1 * z2 - z1 * y2;
  o[1] = w1 * y2 - x1 * z2 + y1 * w2 + z1 * x2;
  o[2] = w1 * z2 + x1 * y2 - y1 * x2 + z1 * w2;
  o[3] = w1 * w2 - x1 * x2 - y1 * y2 - z1 * z2;
}

// C = A @ B
static __device__ __forceinline__ void mm(const float A[9], const float B[9], float C[9]) {
#pragma unroll
  for (int i = 0; i < 3; i++)
#pragma unroll
    for (int j = 0; j < 3; j++)
      C[3 * i + j] = A[3 * i + 0] * B[0 + j] + A[3 * i + 1] * B[3 + j] + A[3 * i + 2] * B[6 + j];
}
// C = A @ B^T
static __device__ __forceinline__ void mmT(const float A[9], const float B[9], float C[9]) {
#pragma unroll
  for (int i = 0; i < 3; i++)
#pragma unroll
    for (int j = 0; j < 3; j++)
      C[3 * i + j] = A[3 * i + 0] * B[3 * j + 0] + A[3 * i + 1] * B[3 * j + 1] + A[3 * i + 2] * B[3 * j + 2];
}
// C = A^T @ B
static __device__ __forceinline__ void mTm(const float A[9], const float B[9], float C[9]) {
#pragma unroll
  for (int i = 0; i < 3; i++)
#pragma unroll
    for (int j = 0; j < 3; j++)
      C[3 * i + j] = A[0 + i] * B[0 + j] + A[3 + i] * B[3 + j] + A[6 + i] * B[6 + j];
}

static __device__ __forceinline__ void expand6(const float c[6], float f[9]) {
  f[0] = c[0]; f[1] = c[1]; f[2] = c[2];
  f[3] = c[1]; f[4] = c[3]; f[5] = c[4];
  f[6] = c[2]; f[7] = c[4]; f[8] = c[5];
}

__device__ __constant__ const int SI6[6] = {0, 0, 0, 1, 1, 2};
__device__ __constant__ const int SJ6[6] = {0, 1, 2, 1, 2, 2};

// One IMU step in hat frame (verified R6-R14). Ro recomputed from s.q.
static __device__ __forceinline__ void step(Seg& s, float gb[3], float dtv,
                                            float omx, float omy, float omz,
                                            float acx, float acy, float acz) {
  float px = omx * dtv, py = omy * dtv, pz = omz * dtv;
  float t2 = px * px + py * py + pz * pz;
  float s_ = 0.5f - t2 * (1.0f / 48.0f);
  float qd[4] = {px * s_, py * s_, pz * s_, 1.0f - 0.125f * t2};

  float Ro[9]; q2m(s.q, Ro);
  float Rd[9]; q2m(qd, Rd);
  float qn[4]; qmul(s.q, qd, qn);
  float Rn[9]; q2m(qn, Rn);

  float gbn[3];
#pragma unroll
  for (int i = 0; i < 3; i++)
    gbn[i] = Rd[0 + i] * gb[0] + Rd[3 + i] * gb[1] + Rd[6 + i] * gb[2];
  float bx = acx - gbn[0], by = acy - gbn[1], bz = acz - gbn[2];
  float Ra[3];
#pragma unroll
  for (int i = 0; i < 3; i++)
    Ra[i] = Ro[3 * i + 0] * bx + Ro[3 * i + 1] * by + Ro[3 * i + 2] * bz;

  float hdt = 0.5f * dtv;
  float hdt2 = hdt * dtv;
#pragma unroll
  for (int i = 0; i < 3; i++) s.dp[i] += s.dv[i] * dtv + Ra[i] * hdt2;
#pragma unroll
  for (int i = 0; i < 3; i++) s.dv[i] += Ra[i] * dtv;

  float M[9];
#pragma unroll
  for (int i = 0; i < 3; i++) {
    M[3 * i + 0] = -dtv * (Rn[3 * i + 1] * acz - Rn[3 * i + 2] * acy);
    M[3 * i + 1] = -dtv * (-Rn[3 * i + 0] * acz + Rn[3 * i + 2] * acx);
    M[3 * i + 2] = -dtv * (Rn[3 * i + 0] * acy - Rn[3 * i + 1] * acx);
  }

  float TP[9]; mmT(M, Ro, TP);
#pragma unroll
  for (int k = 0; k < 9; k++) s.P20[k] += hdt * TP[k] + dtv * s.P10[k];
#pragma unroll
  for (int k = 0; k < 9; k++) s.P10[k] += TP[k];

  float C00f[9]; expand6(s.c00, C00f);
  float W01[9]; mmT(C00f, TP, W01);
  float Y1h[9]; mm(TP, s.c01, Y1h);
  float Y2h[9]; mm(TP, s.c02, Y2h);

  float Wm6[6];
#pragma unroll
  for (int s6 = 0; s6 < 6; s6++) {
    const int i = SI6[s6], j = SJ6[s6];
    Wm6[s6] = W01[0 + i] * TP[3 * j + 0] + W01[3 + i] * TP[3 * j + 1] + W01[6 + i] * TP[3 * j + 2];
  }
  float WmF[9]; expand6(Wm6, WmF);

#pragma unroll
  for (int k = 0; k < 9; k++) s.c02[k] += hdt * (W01[k] + 2.0f * s.c01[k]);
#pragma unroll
  for (int k = 0; k < 9; k++) s.c01[k] += W01[k];

  {
    float ph[3];
#pragma unroll
    for (int i = 0; i < 3; i++)
      ph[i] = Rn[3 * i + 0] * px + Rn[3 * i + 1] * py + Rn[3 * i + 2] * pz;
    float sgdt2 = SIG_G2_C * dtv * dtv;
    float a_ = sgdt2 * (1.0f - t2 * (1.0f / 12.0f));
    float b_ = sgdt2 * ((1.0f / 12.0f) - t2 * (1.0f / 36.0f));
#pragma unroll
    for (int s6 = 0; s6 < 6; s6++) {
      const int i = SI6[s6], j = SJ6[s6];
      float v = s.c00[s6] + b_ * ph[i] * ph[j];
      if (i == j) v += a_;
      s.c00[s6] = v;
    }
  }

  float C11f[9]; expand6(s.c11, C11f);
  float c11p[9];
#pragma unroll
  for (int i = 0; i < 3; i++)
#pragma unroll
    for (int j = 0; j < 3; j++)
      c11p[3 * i + j] = WmF[3 * i + j] + Y1h[3 * i + j] + Y1h[3 * j + i] + C11f[3 * i + j];

  float c12p[9];
#pragma unroll
  for (int i = 0; i < 3; i++)
#pragma unroll
    for (int j = 0; j < 3; j++)
      c12p[3 * i + j] = hdt * (c11p[3 * i + j] + Y1h[3 * i + j] + C11f[3 * i + j])
                      + Y2h[3 * i + j] + s.c12[3 * i + j];

  float dt2v = dtv * dtv;
  float nh2 = -hdt * hdt;
#pragma unroll
  for (int s6 = 0; s6 < 6; s6++) {
    const int i = SI6[s6], j = SJ6[s6];
    float v = s.c22[s6]
            + hdt * (c12p[3 * i + j] + c12p[3 * j + i] + s.c12[3 * i + j] + s.c12[3 * j + i])
            + nh2 * (c11p[3 * i + j] - C11f[3 * i + j]);
    if (i == j) v += SIG_A2_C * 0.25f * dt2v * dt2v;
    s.c22[s6] = v;
  }
#pragma unroll
  for (int i = 0; i < 3; i++)
#pragma unroll
    for (int j = 0; j < 3; j++) {
      float v = c12p[3 * i + j];
      if (i == j) v += SIG_A2_C * hdt * dt2v;
      s.c12[3 * i + j] = v;
    }
#pragma unroll
  for (int s6 = 0; s6 < 6; s6++) {
    const int i = SI6[s6], j = SJ6[s6];
    float v = c11p[3 * i + j];
    if (i == j) v += SIG_A2_C * dt2v;
    s.c11[s6] = v;
  }

#pragma unroll
  for (int i = 0; i < 4; i++) s.q[i] = qn[i];
#pragma unroll
  for (int i = 0; i < 3; i++) gb[i] = gbn[i];
  s.t += dtv;
}

// full sandwich A <- R A R^T
static __device__ __forceinline__ void sandw(const float R[9], float A[9]) {
  float T1[9]; mm(R, A, T1);
  mmT(T1, R, A);
}

// masked shfl_down: identity (0) when lane+d out of range
static __device__ __forceinline__ float shdn(float v, int d, bool ok) {
  float o = __shfl_down(v, d, 64);
  return ok ? o : 0.0f;
}

// Cross-wave compose (verified R12/R14): X = s (regs, earlier half),
// Y = y[74] (LDS, later half). Y's P10/P20 slots hold half-aggregate N1/N2.
static __device__ __forceinline__ void compose2(Seg& s, const float* y) {
  float tY = y[4];
  {
    float xq[4] = {s.q[0], s.q[1], s.q[2], s.q[3]};
    float yq[4] = {y[0], y[1], y[2], y[3]};
    qmul(xq, yq, s.q);
  }
  s.t += tY;
#pragma unroll
  for (int i = 0; i < 3; i++) s.dp[i] += tY * s.dv[i] + y[8 + i];
#pragma unroll
  for (int i = 0; i < 3; i++) s.dv[i] += y[5 + i];

  float N1[9], N2[9];
#pragma unroll
  for (int k = 0; k < 9; k++) { N1[k] = y[11 + k]; N2[k] = y[20 + k]; }

  float X00f[9]; expand6(s.c00, X00f);
  float K1[9]; mm(N1, X00f, K1);
  float K2[9]; mm(N2, X00f, K2);
#pragma unroll
  for (int s6 = 0; s6 < 6; s6++) s.c00[s6] += y[29 + s6];

  float x01[9], x02[9];
#pragma unroll
  for (int k = 0; k < 9; k++) { x01[k] = s.c01[k]; x02[k] = s.c02[k]; }
  float L1[9]; mm(N1, x01, L1);
  float L2[9]; mm(N2, x01, L2);
  float L3[9]; mm(N1, x02, L3);
  float L4[9]; mm(N2, x02, L4);

#pragma unroll
  for (int i = 0; i < 3; i++)
#pragma unroll
    for (int j = 0; j < 3; j++) {
      s.c01[3 * i + j] = x01[3 * i + j] + K1[3 * j + i] + y[35 + 3 * i + j];
      s.c02[3 * i + j] = x02[3 * i + j] + tY * x01[3 * i + j] + K2[3 * j + i] + y[44 + 3 * i + j];
    }

  float x11[6];
#pragma unroll
  for (int s6 = 0; s6 < 6; s6++) x11[s6] = s.c11[s6];
  float X11f[9]; expand6(x11, X11f);
  float x12[9];
#pragma unroll
  for (int k = 0; k < 9; k++) x12[k] = s.c12[k];

#pragma unroll
  for (int s6 = 0; s6 < 6; s6++) {
    const int i = SI6[s6], j = SJ6[s6];
    float kn = K1[3 * i + 0] * N1[3 * j + 0] + K1[3 * i + 1] * N1[3 * j + 1] + K1[3 * i + 2] * N1[3 * j + 2];
    s.c11[s6] = x11[s6] + L1[3 * i + j] + L1[3 * j + i] + kn + y[53 + s6];
  }
#pragma unroll
  for (int i = 0; i < 3; i++)
#pragma unroll
    for (int j = 0; j < 3; j++) {
      float kn = K1[3 * i + 0] * N2[3 * j + 0] + K1[3 * i + 1] * N2[3 * j + 1] + K1[3 * i + 2] * N2[3 * j + 2];
      s.c12[3 * i + j] = x12[3 * i + j] + L3[3 * i + j] + tY * (L1[3 * i + j] + X11f[3 * i + j])
                       + L2[3 * j + i] + kn + y[59 + 3 * i + j];
    }
  float tY2 = tY * tY;
#pragma unroll
  for (int s6 = 0; s6 < 6; s6++) {
    const int i = SI6[s6], j = SJ6[s6];
    float kn = K2[3 * i + 0] * N2[3 * j + 0] + K2[3 * i + 1] * N2[3 * j + 1] + K2[3 * i + 2] * N2[3 * j + 2];
    s.c22[s6] = s.c22[s6] + kn + L4[3 * i + j] + L4[3 * j + i]
              + tY * (L2[3 * i + j] + L2[3 * j + i] + x12[3 * i + j] + x12[3 * j + i])
              + tY2 * X11f[3 * i + j] + y[68 + s6];
  }
}

// Publish a wave's Seg to LDS with COMPILE-TIME indices only (rule #20).
static __device__ __forceinline__ void publish(const Seg& s, float* o) {
  o[0] = s.q[0]; o[1] = s.q[1]; o[2] = s.q[2]; o[3] = s.q[3];
  o[4] = s.t;
#pragma unroll
  for (int i = 0; i < 3; i++) { o[5 + i] = s.dv[i]; o[8 + i] = s.dp[i]; }
#pragma unroll
  for (int k = 0; k < 9; k++) {
    o[11 + k] = s.P10[k]; o[20 + k] = s.P20[k];
    o[35 + k] = s.c01[k]; o[44 + k] = s.c02[k]; o[59 + k] = s.c12[k];
  }
#pragma unroll
  for (int k = 0; k < 6; k++) {
    o[29 + k] = s.c00[k]; o[53 + k] = s.c11[k]; o[68 + k] = s.c22[k];
  }
}

// 256 threads = 4 waves = 2 batches x 2 half-waves, (B+1)/2 blocks (4096 waves).
// w=2 -> VGPR cap 128 -> 4 waves/SIMD. R14 spilled ~6 floats/lane at this cap;
// R15 moves Q (per-lane) and qT (wave-uniform) to LDS across phase 1 to fit.
__global__ __launch_bounds__(256, 2) void imu_kernel(
    const float* __restrict__ dt, const float* __restrict__ ang, const float* __restrict__ acc,
    const float* __restrict__ pos0, const float* __restrict__ vel0, const float* __restrict__ rot0,
    float* __restrict__ out, int B, int N) {
  int lane = threadIdx.x & 63;
  int wv = threadIdx.x >> 6;
  int bl = wv >> 1;   // batch slot within block (0..1)
  int hf = wv & 1;    // half index
  int b = blockIdx.x * 2 + bl;
  int chunk = N >> 7; // 8 steps per lane

  __shared__ float lds_qh[2][4];
  __shared__ float lds_seg[2][74];
  __shared__ float lds_Qs[4][64][4];  // per-lane Q stash across phase 1
  __shared__ float lds_qT[4][4];      // per-wave half-total rotation stash

  long base = (long)b * N + (long)hf * (N >> 1) + (long)lane * chunk;
  const float* dtp = dt + base;
  const float* angp = ang + base * 3;
  const float* accp = acc + base * 3;

  // ---- pre-pass: chunk rotation product ----
  float qc[4] = {0.f, 0.f, 0.f, 1.f};
#pragma unroll 1
  for (int jb = 0; jb < (chunk >> 2); ++jb) {
    float4 d4 = *reinterpret_cast<const float4*>(dtp + jb * 4);
    float4 g0 = *reinterpret_cast<const float4*>(angp + jb * 12 + 0);
    float4 g1 = *reinterpret_cast<const float4*>(angp + jb * 12 + 4);
    float4 g2 = *reinterpret_cast<const float4*>(angp + jb * 12 + 8);
    float dd[4] = {d4.x, d4.y, d4.z, d4.w};
    float gg[12] = {g0.x, g0.y, g0.z, g0.w, g1.x, g1.y, g1.z, g1.w, g2.x, g2.y, g2.z, g2.w};
#pragma unroll
    for (int u = 0; u < 4; ++u) {
      float dtv = dd[u];
      float px = gg[3 * u + 0] * dtv, py = gg[3 * u + 1] * dtv, pz = gg[3 * u + 2] * dtv;
      float t2 = px * px + py * py + pz * pz;
      float s_ = 0.5f - t2 * (1.0f / 48.0f);
      float qd[4] = {px * s_, py * s_, pz * s_, 1.0f - 0.125f * t2};
      float qn[4]; qmul(qc, qd, qn);
      qc[0] = qn[0]; qc[1] = qn[1]; qc[2] = qn[2]; qc[3] = qn[3];
    }
  }
  // inclusive shuffle-up scan (non-commutative)
#pragma unroll
  for (int d = 1; d < 64; d <<= 1) {
    float o0 = __shfl_up(qc[0], d, 64);
    float o1 = __shfl_up(qc[1], d, 64);
    float o2 = __shfl_up(qc[2], d, 64);
    float o3 = __shfl_up(qc[3], d, 64);
    if (lane >= d) {
      float oq[4] = {o0, o1, o2, o3};
      float nn[4]; qmul(oq, qc, nn);
      qc[0] = nn[0]; qc[1] = nn[1]; qc[2] = nn[2]; qc[3] = nn[3];
    }
  }
  // half-total rotation -> LDS stash (wave-uniform; lane 63 has it)
  if (lane == 63) {
    lds_qT[wv][0] = qc[0]; lds_qT[wv][1] = qc[1]; lds_qT[wv][2] = qc[2]; lds_qT[wv][3] = qc[3];
  }
  // first half publishes its total rotation for the second half's prefix
  if (hf == 0 && lane == 63) {
    lds_qh[bl][0] = qc[0]; lds_qh[bl][1] = qc[1]; lds_qh[bl][2] = qc[2]; lds_qh[bl][3] = qc[3];
  }
  // exclusive local prefix
  float Q[4];
  Q[0] = __shfl_up(qc[0], 1, 64);
  Q[1] = __shfl_up(qc[1], 1, 64);
  Q[2] = __shfl_up(qc[2], 1, 64);
  Q[3] = __shfl_up(qc[3], 1, 64);
  if (lane == 0) { Q[0] = 0.f; Q[1] = 0.f; Q[2] = 0.f; Q[3] = 1.f; }
  __syncthreads();
  if (hf == 1) {
    float q0[4] = {lds_qh[bl][0], lds_qh[bl][1], lds_qh[bl][2], lds_qh[bl][3]};
    float qq[4]; qmul(q0, Q, qq);
    Q[0] = qq[0]; Q[1] = qq[1]; Q[2] = qq[2]; Q[3] = qq[3];
  }

  // per-lane gravity in chunk-start frame: g_l = rot(Q^-1, R0^T g)
  float g_l[3];
  {
    float r0q[4] = {rot0[b * 4 + 0], rot0[b * 4 + 1], rot0[b * 4 + 2], rot0[b * 4 + 3]};
    float R0[9]; q2m(r0q, R0);
    float gp[3] = {R0[6] * GRAVITY_C, R0[7] * GRAVITY_C, R0[8] * GRAVITY_C};
    float qx = -Q[0], qy = -Q[1], qz = -Q[2], qw = Q[3];
    float tx = 2.0f * (qy * gp[2] - qz * gp[1]);
    float ty = 2.0f * (qz * gp[0] - qx * gp[2]);
    float tz = 2.0f * (qx * gp[1] - qy * gp[0]);
    g_l[0] = gp[0] + qw * tx + (qy * tz - qz * ty);
    g_l[1] = gp[1] + qw * ty + (qz * tx - qx * tz);
    g_l[2] = gp[2] + qw * tz + (qx * ty - qy * tx);
  }

  // stash Q in LDS across phase 1 (frees 4 VGPRs; same-wave r/w, no barrier)
  lds_Qs[wv][lane][0] = Q[0]; lds_Qs[wv][lane][1] = Q[1];
  lds_Qs[wv][lane][2] = Q[2]; lds_Qs[wv][lane][3] = Q[3];

  Seg s = {};
  s.q[3] = 1.0f;
  float gb[3] = {g_l[0], g_l[1], g_l[2]};

  // ---- phase 1: 1 step/iter, plain loads (4-wave TLP hides latency) ----
#pragma unroll 1
  for (int j = 0; j < chunk; ++j) {
    float dtv = dtp[j];
    float gx = angp[3 * j + 0], gy = angp[3 * j + 1], gz = angp[3 * j + 2];
    float ax = accp[3 * j + 0], ay = accp[3 * j + 1], az = accp[3 * j + 2];
    step(s, gb, dtv, gx, gy, gz, ax, ay, az);
  }

  // ---- globalize via full-sequence prefix RQ (Q reloaded from LDS) ----
  {
    float Qr[4] = {lds_Qs[wv][lane][0], lds_Qs[wv][lane][1], lds_Qs[wv][lane][2], lds_Qs[wv][lane][3]};
    float RQ[9]; q2m(Qr, RQ);
    float tv[3];
#pragma unroll
    for (int i = 0; i < 3; i++)
      tv[i] = RQ[3 * i + 0] * s.dv[0] + RQ[3 * i + 1] * s.dv[1] + RQ[3 * i + 2] * s.dv[2];
#pragma unroll
    for (int i = 0; i < 3; i++) s.dv[i] = tv[i];
#pragma unroll
    for (int i = 0; i < 3; i++)
      tv[i] = RQ[3 * i + 0] * s.dp[0] + RQ[3 * i + 1] * s.dp[1] + RQ[3 * i + 2] * s.dp[2];
#pragma unroll
    for (int i = 0; i < 3; i++) s.dp[i] = tv[i];
    sandw(RQ, s.P10);
    sandw(RQ, s.P20);
    sandw(RQ, s.c01);
    sandw(RQ, s.c02);
    sandw(RQ, s.c12);
    float F[9];
    expand6(s.c00, F); sandw(RQ, F);
    s.c00[0] = F[0]; s.c00[1] = F[1]; s.c00[2] = F[2]; s.c00[3] = F[4]; s.c00[4] = F[5]; s.c00[5] = F[8];
    expand6(s.c11, F); sandw(RQ, F);
    s.c11[0] = F[0]; s.c11[1] = F[1]; s.c11[2] = F[2]; s.c11[3] = F[4]; s.c11[4] = F[5]; s.c11[5] = F[8];
    expand6(s.c22, F); sandw(RQ, F);
    s.c22[0] = F[0]; s.c22[1] = F[1]; s.c22[2] = F[2]; s.c22[3] = F[4]; s.c22[4] = F[5]; s.c22[5] = F[8];
  }

  // ---- phase 2a: suffix scan of (S1, S2, T) over later chunks in this wave ----
  float S1[9], S2[9], Tt;
  {
    bool ok0 = lane < 63;
#pragma unroll
    for (int k = 0; k < 9; k++) {
      S1[k] = shdn(s.P10[k], 1, ok0);
      S2[k] = shdn(s.P20[k], 1, ok0);
    }
    Tt = shdn(s.t, 1, ok0);
#pragma unroll
    for (int d = 1; d < 64; d <<= 1) {
      bool ok = (lane + d) < 64;
      float fT = shdn(Tt, d, ok);
      float fS1[9], fS2[9];
#pragma unroll
      for (int k = 0; k < 9; k++) { fS1[k] = shdn(S1[k], d, ok); fS2[k] = shdn(S2[k], d, ok); }
#pragma unroll
      for (int k = 0; k < 9; k++) S2[k] = fS2[k] + fT * S1[k] + S2[k];
#pragma unroll
      for (int k = 0; k < 9; k++) S1[k] += fS1[k];
      Tt += fT;
    }
  }

  // ---- phase 2b: lift own blocks by P_i = [[I,0,0],[S1,I,0],[S2,Tt*I,I]] ----
  {
    float A9[9]; expand6(s.c00, A9);
    float ASt[9]; mmT(A9, S1, ASt);
    float AZt[9]; mmT(A9, S2, AZt);
    float SB[9];  mm(S1, s.c01, SB);
    float ZB[9];  mm(S2, s.c01, ZB);
    float ZC[9];  mm(S2, s.c02, ZC);
    float D9[9];  expand6(s.c11, D9);

    float r02[9];
#pragma unroll
    for (int k = 0; k < 9; k++) r02[k] = AZt[k] + Tt * s.c01[k] + s.c02[k];
    float Sr02[9]; mm(S1, r02, Sr02);

    float r01[9];
#pragma unroll
    for (int k = 0; k < 9; k++) r01[k] = ASt[k] + s.c01[k];

    float r11[6];
#pragma unroll
    for (int s6 = 0; s6 < 6; s6++) {
      const int i = SI6[s6], j = SJ6[s6];
      float sast = S1[3 * i + 0] * ASt[0 + j] + S1[3 * i + 1] * ASt[3 + j] + S1[3 * i + 2] * ASt[6 + j];
      r11[s6] = sast + SB[3 * i + j] + SB[3 * j + i] + s.c11[s6];
    }
    float r22[6];
#pragma unroll
    for (int s6 = 0; s6 < 6; s6++) {
      const int i = SI6[s6], j = SJ6[s6];
      float zazt = S2[3 * i + 0] * AZt[0 + j] + S2[3 * i + 1] * AZt[3 + j] + S2[3 * i + 2] * AZt[6 + j];
      r22[s6] = zazt + Tt * (ZB[3 * i + j] + ZB[3 * j + i]) + (ZC[3 * i + j] + ZC[3 * j + i])
              + Tt * Tt * D9[3 * i + j] + Tt * (s.c12[3 * i + j] + s.c12[3 * j + i]) + s.c22[s6];
    }
    float r12[9];
#pragma unroll
    for (int i = 0; i < 3; i++)
#pragma unroll
      for (int j = 0; j < 3; j++)
        r12[3 * i + j] = Sr02[3 * i + j] + ZB[3 * j + i] + Tt * D9[3 * i + j] + s.c12[3 * i + j];

#pragma unroll
    for (int k = 0; k < 9; k++) { s.c01[k] = r01[k]; s.c02[k] = r02[k]; s.c12[k] = r12[k]; }
#pragma unroll
    for (int s6 = 0; s6 < 6; s6++) { s.c11[s6] = r11[s6]; s.c22[s6] = r22[s6]; }
#pragma unroll
    for (int i = 0; i < 3; i++) s.dp[i] += Tt * s.dv[i];
    // half-aggregate N2 contribution: z_i = P20_i + Tt_i * P10_i (hf=1 only uses it)
#pragma unroll
    for (int k = 0; k < 9; k++) s.P20[k] += Tt * s.P10[k];
  }

  // ---- phase 2c: butterfly sums ----
#pragma unroll
  for (int d = 1; d < 64; d <<= 1) {
#pragma unroll
    for (int k = 0; k < 6; k++) s.c00[k] += __shfl_xor(s.c00[k], d, 64);
#pragma unroll
    for (int k = 0; k < 9; k++) s.c01[k] += __shfl_xor(s.c01[k], d, 64);
#pragma unroll
    for (int k = 0; k < 9; k++) s.c02[k] += __shfl_xor(s.c02[k], d, 64);
#pragma unroll
    for (int k = 0; k < 6; k++) s.c11[k] += __shfl_xor(s.c11[k], d, 64);
#pragma unroll
    for (int k = 0; k < 9; k++) s.c12[k] += __shfl_xor(s.c12[k], d, 64);
#pragma unroll
    for (int k = 0; k < 6; k++) s.c22[k] += __shfl_xor(s.c22[k], d, 64);
#pragma unroll
    for (int k = 0; k < 3; k++) { s.dv[k] += __shfl_xor(s.dv[k], d, 64); s.dp[k] += __shfl_xor(s.dp[k], d, 64); }
    s.t += __shfl_xor(s.t, d, 64);
  }
  if (hf == 1) {
    // only the later half's N1/N2 aggregates feed compose2
#pragma unroll
    for (int d = 1; d < 64; d <<= 1) {
#pragma unroll
      for (int k = 0; k < 9; k++) { s.P10[k] += __shfl_xor(s.P10[k], d, 64); s.P20[k] += __shfl_xor(s.P20[k], d, 64); }
    }
  }
  // set q to the half-total rotation (reload from LDS stash)
  s.q[0] = lds_qT[wv][0]; s.q[1] = lds_qT[wv][1]; s.q[2] = lds_qT[wv][2]; s.q[3] = lds_qT[wv][3];

  // ---- cross-wave merge: second half publishes (STATIC indices), first composes ----
  if (hf == 1 && lane == 0) publish(s, lds_seg[bl]);
  __syncthreads();

  if (hf == 0 && lane == 0) {
    compose2(s, lds_seg[bl]);

    float r0q[4] = {rot0[b * 4 + 0], rot0[b * 4 + 1], rot0[b * 4 + 2], rot0[b * 4 + 3]};
    float p0[3] = {pos0[b * 3 + 0], pos0[b * 3 + 1], pos0[b * 3 + 2]};
    float v0[3] = {vel0[b * 3 + 0], vel0[b * 3 + 1], vel0[b * 3 + 2]};
    float R0[9]; q2m(r0q, R0);
    float qo[4]; qmul(r0q, s.q, qo);
#pragma unroll
    for (int i = 0; i < 4; i++) out[b * 4 + i] = qo[i];
#pragma unroll
    for (int i = 0; i < 3; i++) {
      float vv = v0[i] + R0[3 * i + 0] * s.dv[0] + R0[3 * i + 1] * s.dv[1] + R0[3 * i + 2] * s.dv[2];
      float pv = p0[i] + v0[i] * s.t + R0[3 * i + 0] * s.dp[0] + R0[3 * i + 1] * s.dp[1] + R0[3 * i + 2] * s.dp[2];
      out[4 * B + b * 3 + i] = vv;
      out[7 * B + b * 3 + i] = pv;
    }
    // convert theta-indexed blocks back to end-body frame convention
    float Rq[9]; q2m(s.q, Rq);
    float C00f[9];
    {
      float G[9]; expand6(s.c00, G);
      float T1[9]; mTm(Rq, G, T1);
      mm(T1, Rq, C00f);
    }
    float C01f[9]; mTm(Rq, s.c01, C01f);
    float C02f[9]; mTm(Rq, s.c02, C02f);
    float C11f[9], C22f[9];
    expand6(s.c11, C11f); expand6(s.c22, C22f);

    long cb = 10L * B + (long)b * 81;
#pragma unroll
    for (int i = 0; i < 3; i++)
#pragma unroll
      for (int j = 0; j < 3; j++) {
        out[cb + i * 9 + j]           = C00f[3 * i + j];
        out[cb + i * 9 + (j + 3)]     = C01f[3 * i + j];
        out[cb + i * 9 + (j + 6)]     = C02f[3 * i + j];
        out[cb + (i + 3) * 9 + j]     = C01f[3 * j + i];
        out[cb + (i + 3) * 9 + j + 3] = C11f[3 * i + j];
        out[cb + (i + 3) * 9 + j + 6] = s.c12[3 * i + j];
        out[cb + (i + 6) * 9 + j]     = C02f[3 * j + i];
        out[cb + (i + 6) * 9 + j + 3] = s.c12[3 * j + i];
        out[cb + (i + 6) * 9 + j + 6] = C22f[3 * i + j];
      }
  }
}

extern "C" void kernel_launch(void* const* d_in, const int* in_sizes, int n_in,
                              void* d_out, int out_size, void* d_ws, size_t ws_size,
                              hipStream_t stream) {
  const float* dt   = (const float*)d_in[0];
  const float* ang  = (const float*)d_in[1];
  const float* acc  = (const float*)d_in[2];
  const float* pos0 = (const float*)d_in[3];
  const float* vel0 = (const float*)d_in[4];
  const float* rot0 = (const float*)d_in[5];
  int B = in_sizes[5] / 4;
  int N = in_sizes[0] / B;
  float* out = (float*)d_out;
  dim3 grid((B + 1) / 2), block(256);
  imu_kernel<<<grid, block, 0, stream>>>(dt, ang, acc, pos0, vel0, rot0, out, B, N);
}

// Round 16
// 71.015 us; speedup vs baseline: 1.0426x; 1.0199x over previous
//
#include <hip/hip_runtime.h>
#include <math.h>

#define GRAVITY_C 9.81007f
#define SIG_G2_C (1.6968e-4f * 1.6968e-4f)
#define SIG_A2_C (2.0e-3f * 2.0e-3f)

// Segment summary (74 floats); phase-2 uses suffix-scan + lift + sums
// (closed form of the verified R7-R12 global-frame composition).
struct Seg {
  float q[4];
  float t;
  float dv[3], dp[3];
  float P10[9], P20[9];
  float c00[6], c01[9], c02[9], c11[6], c12[9], c22[6];
};

static __device__ __forceinline__ void q2m(const float q[4], float R[9]) {
  float x = q[0], y = q[1], z = q[2], w = q[3];
  R[0] = 1.f - 2.f * (y * y + z * z); R[1] = 2.f * (x * y - z * w);       R[2] = 2.f * (x * z + y * w);
  R[3] = 2.f * (x * y + z * w);       R[4] = 1.f - 2.f * (x * x + z * z); R[5] = 2.f * (y * z - x * w);
  R[6] = 2.f * (x * z - y * w);       R[7] = 2.f * (y * z + x * w);       R[8] = 1.f - 2.f * (x * x + y * y);
}

static __device__ __forceinline__ void qmul(const float a[4], const float b[4], float o[4]) {
  float x1 = a[0], y1 = a[1], z1 = a[2], w1 = a[3];
  float x2 = b[0], y2 = b[1], z2 = b[2], w2 = b[3];
  o[0] = w1 * x2 + x1 * w2 + y1 * z2 - z1 * y2;
  o[1] = w1 * y2 - x1 * z2 + y1 * w2 + z1 * x2;
  o[2] = w1 * z2 + x1 * y2 - y1 * x2 + z1 * w2;
  o[3] = w1 * w2 - x1 * x2 - y1 * y2 - z1 * z2;
}

// C = A @ B
static __device__ __forceinline__ void mm(const float A[9], const float B[9], float C[9]) {
#pragma unroll
  for (int i = 0; i < 3; i++)
#pragma unroll
    for (int j = 0; j < 3; j++)
      C[3 * i + j] = A[3 * i + 0] * B[0 + j] + A[3 * i + 1] * B[3 + j] + A[3 * i + 2] * B[6 + j];
}
// C = A @ B^T
static __device__ __forceinline__ void mmT(const float A[9], const float B[9], float C[9]) {
#pragma unroll
  for (int i = 0; i < 3; i++)
#pragma unroll
    for (int j = 0; j < 3; j++)
      C[3 * i + j] = A[3 * i + 0] * B[3 * j + 0] + A[3 * i + 1] * B[3 * j + 1] + A[3 * i + 2] * B[3 * j + 2];
}
// C = A^T @ B
static __device__ __forceinline__ void mTm(const float A[9], const float B[9], float C[9]) {
#pragma unroll
  for (int i = 0; i < 3; i++)
#pragma unroll
    for (int j = 0; j < 3; j++)
      C[3 * i + j] = A[0 + i] * B[0 + j] + A[3 + i] * B[3 + j] + A[6 + i] * B[6 + j];
}

static __device__ __forceinline__ void expand6(const float c[6], float f[9]) {
  f[0] = c[0]; f[1] = c[1]; f[2] = c[2];
  f[3] = c[1]; f[4] = c[3]; f[5] = c[4];
  f[6] = c[2]; f[7] = c[4]; f[8] = c[5];
}

__device__ __constant__ const int SI6[6] = {0, 0, 0, 1, 1, 2};
__device__ __constant__ const int SJ6[6] = {0, 1, 2, 1, 2, 2};

// One IMU step in hat frame (verified R6-R12). Ro carried.
static __device__ __forceinline__ void step(Seg& s, float Ro[9], float gb[3], float dtv,
                                            float omx, float omy, float omz,
                                            float acx, float acy, float acz) {
  float px = omx * dtv, py = omy * dtv, pz = omz * dtv;
  float t2 = px * px + py * py + pz * pz;
  float s_ = 0.5f - t2 * (1.0f / 48.0f);
  float qd[4] = {px * s_, py * s_, pz * s_, 1.0f - 0.125f * t2};

  float Rd[9]; q2m(qd, Rd);
  float qn[4]; qmul(s.q, qd, qn);
  float Rn[9]; q2m(qn, Rn);

  float gbn[3];
#pragma unroll
  for (int i = 0; i < 3; i++)
    gbn[i] = Rd[0 + i] * gb[0] + Rd[3 + i] * gb[1] + Rd[6 + i] * gb[2];
  float bx = acx - gbn[0], by = acy - gbn[1], bz = acz - gbn[2];
  float Ra[3];
#pragma unroll
  for (int i = 0; i < 3; i++)
    Ra[i] = Ro[3 * i + 0] * bx + Ro[3 * i + 1] * by + Ro[3 * i + 2] * bz;

  float hdt = 0.5f * dtv;
  float hdt2 = hdt * dtv;
#pragma unroll
  for (int i = 0; i < 3; i++) s.dp[i] += s.dv[i] * dtv + Ra[i] * hdt2;
#pragma unroll
  for (int i = 0; i < 3; i++) s.dv[i] += Ra[i] * dtv;

  float M[9];
#pragma unroll
  for (int i = 0; i < 3; i++) {
    M[3 * i + 0] = -dtv * (Rn[3 * i + 1] * acz - Rn[3 * i + 2] * acy);
    M[3 * i + 1] = -dtv * (-Rn[3 * i + 0] * acz + Rn[3 * i + 2] * acx);
    M[3 * i + 2] = -dtv * (Rn[3 * i + 0] * acy - Rn[3 * i + 1] * acx);
  }

  float TP[9]; mmT(M, Ro, TP);
#pragma unroll
  for (int k = 0; k < 9; k++) s.P20[k] += hdt * TP[k] + dtv * s.P10[k];
#pragma unroll
  for (int k = 0; k < 9; k++) s.P10[k] += TP[k];

  float C00f[9]; expand6(s.c00, C00f);
  float W01[9]; mmT(C00f, TP, W01);
  float Y1h[9]; mm(TP, s.c01, Y1h);
  float Y2h[9]; mm(TP, s.c02, Y2h);

  float Wm6[6];
#pragma unroll
  for (int s6 = 0; s6 < 6; s6++) {
    const int i = SI6[s6], j = SJ6[s6];
    Wm6[s6] = W01[0 + i] * TP[3 * j + 0] + W01[3 + i] * TP[3 * j + 1] + W01[6 + i] * TP[3 * j + 2];
  }
  float WmF[9]; expand6(Wm6, WmF);

#pragma unroll
  for (int k = 0; k < 9; k++) s.c02[k] += hdt * (W01[k] + 2.0f * s.c01[k]);
#pragma unroll
  for (int k = 0; k < 9; k++) s.c01[k] += W01[k];

  {
    float ph[3];
#pragma unroll
    for (int i = 0; i < 3; i++)
      ph[i] = Rn[3 * i + 0] * px + Rn[3 * i + 1] * py + Rn[3 * i + 2] * pz;
    float sgdt2 = SIG_G2_C * dtv * dtv;
    float a_ = sgdt2 * (1.0f - t2 * (1.0f / 12.0f));
    float b_ = sgdt2 * ((1.0f / 12.0f) - t2 * (1.0f / 36.0f));
#pragma unroll
    for (int s6 = 0; s6 < 6; s6++) {
      const int i = SI6[s6], j = SJ6[s6];
      float v = s.c00[s6] + b_ * ph[i] * ph[j];
      if (i == j) v += a_;
      s.c00[s6] = v;
    }
  }

  float C11f[9]; expand6(s.c11, C11f);
  float c11p[9];
#pragma unroll
  for (int i = 0; i < 3; i++)
#pragma unroll
    for (int j = 0; j < 3; j++)
      c11p[3 * i + j] = WmF[3 * i + j] + Y1h[3 * i + j] + Y1h[3 * j + i] + C11f[3 * i + j];

  float c12p[9];
#pragma unroll
  for (int i = 0; i < 3; i++)
#pragma unroll
    for (int j = 0; j < 3; j++)
      c12p[3 * i + j] = hdt * (c11p[3 * i + j] + Y1h[3 * i + j] + C11f[3 * i + j])
                      + Y2h[3 * i + j] + s.c12[3 * i + j];

  float dt2v = dtv * dtv;
  float nh2 = -hdt * hdt;
#pragma unroll
  for (int s6 = 0; s6 < 6; s6++) {
    const int i = SI6[s6], j = SJ6[s6];
    float v = s.c22[s6]
            + hdt * (c12p[3 * i + j] + c12p[3 * j + i] + s.c12[3 * i + j] + s.c12[3 * j + i])
            + nh2 * (c11p[3 * i + j] - C11f[3 * i + j]);
    if (i == j) v += SIG_A2_C * 0.25f * dt2v * dt2v;
    s.c22[s6] = v;
  }
#pragma unroll
  for (int i = 0; i < 3; i++)
#pragma unroll
    for (int j = 0; j < 3; j++) {
      float v = c12p[3 * i + j];
      if (i == j) v += SIG_A2_C * hdt * dt2v;
      s.c12[3 * i + j] = v;
    }
#pragma unroll
  for (int s6 = 0; s6 < 6; s6++) {
    const int i = SI6[s6], j = SJ6[s6];
    float v = c11p[3 * i + j];
    if (i == j) v += SIG_A2_C * dt2v;
    s.c11[s6] = v;
  }

#pragma unroll
  for (int i = 0; i < 4; i++) s.q[i] = qn[i];
#pragma unroll
  for (int k = 0; k < 9; k++) Ro[k] = Rn[k];
#pragma unroll
  for (int i = 0; i < 3; i++) gb[i] = gbn[i];
  s.t += dtv;
}

// full sandwich A <- R A R^T
static __device__ __forceinline__ void sandw(const float R[9], float A[9]) {
  float T1[9]; mm(R, A, T1);
  mmT(T1, R, A);
}

// masked shfl_down: identity (0) when lane+d out of range
static __device__ __forceinline__ float shdn(float v, int d, bool ok) {
  float o = __shfl_down(v, d, 64);
  return ok ? o : 0.0f;
}

__global__ __launch_bounds__(256, 1) void imu_kernel(
    const float* __restrict__ dt, const float* __restrict__ ang, const float* __restrict__ acc,
    const float* __restrict__ pos0, const float* __restrict__ vel0, const float* __restrict__ rot0,
    float* __restrict__ out, int B, int N) {
  int lane = threadIdx.x & 63;
  int wave = threadIdx.x >> 6;
  int b = blockIdx.x * 4 + wave;
  if (b >= B) return;
  int chunk = N >> 6; // 16 steps per lane

  long base = (long)b * N + (long)lane * chunk;
  const float* dtp = dt + base;
  const float* angp = ang + base * 3;
  const float* accp = acc + base * 3;

  // ---- pre-pass: chunk rotation product (float4 loads, Taylor exp) ----
  float qc[4] = {0.f, 0.f, 0.f, 1.f};
#pragma unroll 1
  for (int jb = 0; jb < (chunk >> 2); ++jb) {
    float4 d4 = *reinterpret_cast<const float4*>(dtp + jb * 4);
    float4 g0 = *reinterpret_cast<const float4*>(angp + jb * 12 + 0);
    float4 g1 = *reinterpret_cast<const float4*>(angp + jb * 12 + 4);
    float4 g2 = *reinterpret_cast<const float4*>(angp + jb * 12 + 8);
    float dd[4] = {d4.x, d4.y, d4.z, d4.w};
    float gg[12] = {g0.x, g0.y, g0.z, g0.w, g1.x, g1.y, g1.z, g1.w, g2.x, g2.y, g2.z, g2.w};
#pragma unroll
    for (int u = 0; u < 4; ++u) {
      float dtv = dd[u];
      float px = gg[3 * u + 0] * dtv, py = gg[3 * u + 1] * dtv, pz = gg[3 * u + 2] * dtv;
      float t2 = px * px + py * py + pz * pz;
      float s_ = 0.5f - t2 * (1.0f / 48.0f);
      float qd[4] = {px * s_, py * s_, pz * s_, 1.0f - 0.125f * t2};
      float qn[4]; qmul(qc, qd, qn);
      qc[0] = qn[0]; qc[1] = qn[1]; qc[2] = qn[2]; qc[3] = qn[3];
    }
  }
  // inclusive shuffle-up scan (non-commutative)
#pragma unroll
  for (int d = 1; d < 64; d <<= 1) {
    float o0 = __shfl_up(qc[0], d, 64);
    float o1 = __shfl_up(qc[1], d, 64);
    float o2 = __shfl_up(qc[2], d, 64);
    float o3 = __shfl_up(qc[3], d, 64);
    if (lane >= d) {
      float oq[4] = {o0, o1, o2, o3};
      float nn[4]; qmul(oq, qc, nn);
      qc[0] = nn[0]; qc[1] = nn[1]; qc[2] = nn[2]; qc[3] = nn[3];
    }
  }
  // total batch rotation = inclusive prefix at lane 63 (broadcast)
  float qT[4];
  qT[0] = __shfl(qc[0], 63, 64);
  qT[1] = __shfl(qc[1], 63, 64);
  qT[2] = __shfl(qc[2], 63, 64);
  qT[3] = __shfl(qc[3], 63, 64);
  // exclusive prefix Q
  float Q[4];
  Q[0] = __shfl_up(qc[0], 1, 64);
  Q[1] = __shfl_up(qc[1], 1, 64);
  Q[2] = __shfl_up(qc[2], 1, 64);
  Q[3] = __shfl_up(qc[3], 1, 64);
  if (lane == 0) { Q[0] = 0.f; Q[1] = 0.f; Q[2] = 0.f; Q[3] = 1.f; }

  // per-lane gravity in chunk-start frame: g_l = rot(Q^-1, R0^T g)
  float g_l[3];
  {
    float r0q[4] = {rot0[b * 4 + 0], rot0[b * 4 + 1], rot0[b * 4 + 2], rot0[b * 4 + 3]};
    float R0[9]; q2m(r0q, R0);
    float gp[3] = {R0[6] * GRAVITY_C, R0[7] * GRAVITY_C, R0[8] * GRAVITY_C};
    float qx = -Q[0], qy = -Q[1], qz = -Q[2], qw = Q[3];
    float tx = 2.0f * (qy * gp[2] - qz * gp[1]);
    float ty = 2.0f * (qz * gp[0] - qx * gp[2]);
    float tz = 2.0f * (qx * gp[1] - qy * gp[0]);
    g_l[0] = gp[0] + qw * tx + (qy * tz - qz * ty);
    g_l[1] = gp[1] + qw * ty + (qz * tx - qx * tz);
    g_l[2] = gp[2] + qw * tz + (qx * ty - qy * tx);
  }

  Seg s = {};
  s.q[3] = 1.0f;
  float Ro[9] = {1.f, 0.f, 0.f, 0.f, 1.f, 0.f, 0.f, 0.f, 1.f};
  float gb[3] = {g_l[0], g_l[1], g_l[2]};

  // ---- phase 1: 1 step/iter with 1-deep prefetch (R8 shape) ----
  float dc = dtp[0];
  float gx = angp[0], gy = angp[1], gz = angp[2];
  float ax = accp[0], ay = accp[1], az = accp[2];
#pragma unroll 1
  for (int j = 0; j < chunk; ++j) {
    int jn = (j + 1 < chunk) ? j + 1 : j;
    float dn = dtp[jn];
    float gnx = angp[3 * jn + 0], gny = angp[3 * jn + 1], gnz = angp[3 * jn + 2];
    float anx = accp[3 * jn + 0], any2 = accp[3 * jn + 1], anz = accp[3 * jn + 2];
    step(s, Ro, gb, dc, gx, gy, gz, ax, ay, az);
    dc = dn; gx = gnx; gy = gny; gz = gnz; ax = anx; ay = any2; az = anz;
  }

  // ---- globalize: every block -> sequence-start frame via RQ ----
  {
    float RQ[9]; q2m(Q, RQ);
    float tv[3];
#pragma unroll
    for (int i = 0; i < 3; i++)
      tv[i] = RQ[3 * i + 0] * s.dv[0] + RQ[3 * i + 1] * s.dv[1] + RQ[3 * i + 2] * s.dv[2];
#pragma unroll
    for (int i = 0; i < 3; i++) s.dv[i] = tv[i];
#pragma unroll
    for (int i = 0; i < 3; i++)
      tv[i] = RQ[3 * i + 0] * s.dp[0] + RQ[3 * i + 1] * s.dp[1] + RQ[3 * i + 2] * s.dp[2];
#pragma unroll
    for (int i = 0; i < 3; i++) s.dp[i] = tv[i];
    sandw(RQ, s.P10);
    sandw(RQ, s.P20);
    sandw(RQ, s.c01);
    sandw(RQ, s.c02);
    sandw(RQ, s.c12);
    float F[9];
    expand6(s.c00, F); sandw(RQ, F);
    s.c00[0] = F[0]; s.c00[1] = F[1]; s.c00[2] = F[2]; s.c00[3] = F[4]; s.c00[4] = F[5]; s.c00[5] = F[8];
    expand6(s.c11, F); sandw(RQ, F);
    s.c11[0] = F[0]; s.c11[1] = F[1]; s.c11[2] = F[2]; s.c11[3] = F[4]; s.c11[4] = F[5]; s.c11[5] = F[8];
    expand6(s.c22, F); sandw(RQ, F);
    s.c22[0] = F[0]; s.c22[1] = F[1]; s.c22[2] = F[2]; s.c22[3] = F[4]; s.c22[4] = F[5]; s.c22[5] = F[8];
  }

  // ---- phase 2a: suffix scan of (S1, S2, T) over later chunks ----
  // state_i = A_63 ... A_{i+1} = [[I,0,0],[S1,I,0],[S2, T*I, I]];
  // combine(far=later, near=earlier): S1=S1f+S1n; S2=S2f+Tf*S1n+S2n; T=Tf+Tn.
  float S1[9], S2[9], Tt;
  {
    bool ok0 = lane < 63;
#pragma unroll
    for (int k = 0; k < 9; k++) {
      S1[k] = shdn(s.P10[k], 1, ok0);
      S2[k] = shdn(s.P20[k], 1, ok0);
    }
    Tt = shdn(s.t, 1, ok0);
#pragma unroll
    for (int d = 1; d < 64; d <<= 1) {
      bool ok = (lane + d) < 64;
      float fT = shdn(Tt, d, ok);
      float fS1[9], fS2[9];
#pragma unroll
      for (int k = 0; k < 9; k++) { fS1[k] = shdn(S1[k], d, ok); fS2[k] = shdn(S2[k], d, ok); }
      // S2 first (uses old S1)
#pragma unroll
      for (int k = 0; k < 9; k++) S2[k] = fS2[k] + fT * S1[k] + S2[k];
#pragma unroll
      for (int k = 0; k < 9; k++) S1[k] += fS1[k];
      Tt += fT;
    }
  }

  // ---- phase 2b: lift own blocks by P_i = [[I,0,0],[S1,I,0],[S2,Tt*I,I]] ----
  // cov_total = sum_i P_i cov_i P_i^T ; dp_i' = dp_i + Tt*dv_i
  {
    float A9[9]; expand6(s.c00, A9);
    float ASt[9]; mmT(A9, S1, ASt);   // A S1^T
    float AZt[9]; mmT(A9, S2, AZt);   // A S2^T
    float SB[9];  mm(S1, s.c01, SB);  // S1 B
    float ZB[9];  mm(S2, s.c01, ZB);  // S2 B
    float ZC[9];  mm(S2, s.c02, ZC);  // S2 C
    float D9[9];  expand6(s.c11, D9);

    float r02[9];
#pragma unroll
    for (int k = 0; k < 9; k++) r02[k] = AZt[k] + Tt * s.c01[k] + s.c02[k];
    float Sr02[9]; mm(S1, r02, Sr02);

    // r01
    float r01[9];
#pragma unroll
    for (int k = 0; k < 9; k++) r01[k] = ASt[k] + s.c01[k];

    // r11 (sym)
    float r11[6];
#pragma unroll
    for (int s6 = 0; s6 < 6; s6++) {
      const int i = SI6[s6], j = SJ6[s6];
      float sast = S1[3 * i + 0] * ASt[0 + j] + S1[3 * i + 1] * ASt[3 + j] + S1[3 * i + 2] * ASt[6 + j];
      r11[s6] = sast + SB[3 * i + j] + SB[3 * j + i] + s.c11[s6];
    }
    // r22 (sym)
    float r22[6];
#pragma unroll
    for (int s6 = 0; s6 < 6; s6++) {
      const int i = SI6[s6], j = SJ6[s6];
      float zazt = S2[3 * i + 0] * AZt[0 + j] + S2[3 * i + 1] * AZt[3 + j] + S2[3 * i + 2] * AZt[6 + j];
      r22[s6] = zazt + Tt * (ZB[3 * i + j] + ZB[3 * j + i]) + (ZC[3 * i + j] + ZC[3 * j + i])
              + Tt * Tt * D9[3 * i + j] + Tt * (s.c12[3 * i + j] + s.c12[3 * j + i]) + s.c22[s6];
    }
    // r12 = S1*r02 + (ZB)^T + Tt*D + E
    float r12[9];
#pragma unroll
    for (int i = 0; i < 3; i++)
#pragma unroll
      for (int j = 0; j < 3; j++)
        r12[3 * i + j] = Sr02[3 * i + j] + ZB[3 * j + i] + Tt * D9[3 * i + j] + s.c12[3 * i + j];

    // commit (c00 unchanged: r00 = A)
#pragma unroll
    for (int k = 0; k < 9; k++) { s.c01[k] = r01[k]; s.c02[k] = r02[k]; s.c12[k] = r12[k]; }
#pragma unroll
    for (int s6 = 0; s6 < 6; s6++) { s.c11[s6] = r11[s6]; s.c22[s6] = r22[s6]; }
    // dp lift
#pragma unroll
    for (int i = 0; i < 3; i++) s.dp[i] += Tt * s.dv[i];
  }

  // ---- phase 2c: plain butterfly sums (52 floats) ----
#pragma unroll
  for (int d = 1; d < 64; d <<= 1) {
#pragma unroll
    for (int k = 0; k < 6; k++) s.c00[k] += __shfl_xor(s.c00[k], d, 64);
#pragma unroll
    for (int k = 0; k < 9; k++) s.c01[k] += __shfl_xor(s.c01[k], d, 64);
#pragma unroll
    for (int k = 0; k < 9; k++) s.c02[k] += __shfl_xor(s.c02[k], d, 64);
#pragma unroll
    for (int k = 0; k < 6; k++) s.c11[k] += __shfl_xor(s.c11[k], d, 64);
#pragma unroll
    for (int k = 0; k < 9; k++) s.c12[k] += __shfl_xor(s.c12[k], d, 64);
#pragma unroll
    for (int k = 0; k < 6; k++) s.c22[k] += __shfl_xor(s.c22[k], d, 64);
#pragma unroll
    for (int k = 0; k < 3; k++) { s.dv[k] += __shfl_xor(s.dv[k], d, 64); s.dp[k] += __shfl_xor(s.dp[k], d, 64); }
    s.t += __shfl_xor(s.t, d, 64);
  }

  if (lane == 0) {
    float r0q[4] = {rot0[b * 4 + 0], rot0[b * 4 + 1], rot0[b * 4 + 2], rot0[b * 4 + 3]};
    float p0[3] = {pos0[b * 3 + 0], pos0[b * 3 + 1], pos0[b * 3 + 2]};
    float v0[3] = {vel0[b * 3 + 0], vel0[b * 3 + 1], vel0[b * 3 + 2]};
    float R0[9]; q2m(r0q, R0);
    float qo[4]; qmul(r0q, qT, qo);
#pragma unroll
    for (int i = 0; i < 4; i++) out[b * 4 + i] = qo[i];
#pragma unroll
    for (int i = 0; i < 3; i++) {
      float vv = v0[i] + R0[3 * i + 0] * s.dv[0] + R0[3 * i + 1] * s.dv[1] + R0[3 * i + 2] * s.dv[2];
      float pv = p0[i] + v0[i] * s.t + R0[3 * i + 0] * s.dp[0] + R0[3 * i + 1] * s.dp[1] + R0[3 * i + 2] * s.dp[2];
      out[4 * B + b * 3 + i] = vv;
      out[7 * B + b * 3 + i] = pv;
    }
    // convert theta-indexed blocks back to end-body frame convention
    float Rq[9]; q2m(qT, Rq);
    float C00f[9];
    {
      float G[9]; expand6(s.c00, G);
      float T1[9]; mTm(Rq, G, T1);
      mm(T1, Rq, C00f);
    }
    float C01f[9]; mTm(Rq, s.c01, C01f);
    float C02f[9]; mTm(Rq, s.c02, C02f);
    float C11f[9], C22f[9];
    expand6(s.c11, C11f); expand6(s.c22, C22f);

    long cb = 10L * B + (long)b * 81;
#pragma unroll
    for (int i = 0; i < 3; i++)
#pragma unroll
      for (int j = 0; j < 3; j++) {
        out[cb + i * 9 + j]           = C00f[3 * i + j];
        out[cb + i * 9 + (j + 3)]     = C01f[3 * i + j];
        out[cb + i * 9 + (j + 6)]     = C02f[3 * i + j];
        out[cb + (i + 3) * 9 + j]     = C01f[3 * j + i];
        out[cb + (i + 3) * 9 + j + 3] = C11f[3 * i + j];
        out[cb + (i + 3) * 9 + j + 6] = s.c12[3 * i + j];
        out[cb + (i + 6) * 9 + j]     = C02f[3 * j + i];
        out[cb + (i + 6) * 9 + j + 3] = s.c12[3 * j + i];
        out[cb + (i + 6) * 9 + j + 6] = C22f[3 * i + j];
      }
  }
}

extern "C" void kernel_launch(void* const* d_in, const int* in_sizes, int n_in,
                              void* d_out, int out_size, void* d_ws, size_t ws_size,
                              hipStream_t stream) {
  const float* dt   = (const float*)d_in[0];
  const float* ang  = (const float*)d_in[1];
  const float* acc  = (const float*)d_in[2];
  const float* pos0 = (const float*)d_in[3];
  const float* vel0 = (const float*)d_in[4];
  const float* rot0 = (const float*)d_in[5];
  int B = in_sizes[5] / 4;
  int N = in_sizes[0] / B;
  float* out = (float*)d_out;
  dim3 grid((B + 3) / 4), block(256);
  imu_kernel<<<grid, block, 0, stream>>>(dt, ang, acc, pos0, vel0, rot0, out, B, N);
}